// Round 5
// baseline (1581.432 us; speedup 1.0000x reference)
//
#include <hip/hip_runtime.h>
#include <hip/hip_bf16.h>

#define N_NODES   100000
#define N_EDGES   1600000
#define NUM_GRAPHS 1000

typedef unsigned int u32;
typedef unsigned short u16;

typedef __bf16 bf16_t;
typedef bf16_t bf16x8 __attribute__((ext_vector_type(8)));
typedef float  f32x4  __attribute__((ext_vector_type(4)));

__device__ __forceinline__ float bf2f(u16 u){ return __uint_as_float(((u32)u)<<16); }
__device__ __forceinline__ float BL(u32 u){ return __uint_as_float(u<<16); }
__device__ __forceinline__ float BH(u32 u){ return __uint_as_float(u&0xffff0000u); }
// f32 -> bf16 bits, round-to-nearest-even
__device__ __forceinline__ u16 f2bf(float f){
  u32 u = __float_as_uint(f);
  return (u16)((u + 0x7fffu + ((u>>16)&1u)) >> 16);
}
// dual-dtype scalar load: isbf=1 -> bf16, else f32
__device__ __forceinline__ float ldf(const void* p, size_t i, int isbf){
  return isbf ? bf2f(((const u16*)p)[i]) : ((const float*)p)[i];
}

union U4BF { uint4 u; bf16x8 v; };

// ---------------- dtype detector ----------------
__global__ void k_detect(const u32* __restrict__ x, int* __restrict__ flag){
  int t = threadIdx.x; int cnt = 0;
  for (int i = t; i < 256; i += 64){
    u32 w = x[i];
    u32 e = (w >> 7) & 0xffu;
    if (e >= 110u && e <= 137u) cnt++;
  }
  for (int o = 32; o; o >>= 1) cnt += __shfl_xor(cnt, o);
  if (t == 0) *flag = (cnt > 128) ? 1 : 0;
}

// ---------------- weight prep: bf16 Wcol[l][c][96]; eff[0]=orig; uaff=id ----
// k 0..63 msg_W1 | 64..79 folded edge emb | 80 folded bias (A pad col = 1.0) | 81..95 zero
__global__ void k_prep(const void* __restrict__ eW, const void* __restrict__ eb,
                       const void* __restrict__ mW, const void* __restrict__ mb,
                       u16* __restrict__ Wcol, u16* __restrict__ Weff,
                       float* __restrict__ uaff, const int* __restrict__ flagp){
  int isbf = *flagp;
  int l = blockIdx.x, c = threadIdx.x;
  u16* W = Wcol + ((size_t)l*64 + c)*96;
  for (int k = 0; k < 64; k++)
    W[k] = f2bf(ldf(mW, (size_t)(l*96 + k)*64 + c, isbf));
  for (int j = 0; j < 16; j++){
    float acc = 0.f;
    for (int k = 0; k < 32; k++)
      acc += ldf(eW, (size_t)j*32 + k, isbf) * ldf(mW, (size_t)(l*96 + 64 + k)*64 + c, isbf);
    W[64 + j] = f2bf(acc);
  }
  float fbv = ldf(mb, (size_t)l*64 + c, isbf);
  for (int k = 0; k < 32; k++)
    fbv += ldf(eb, k, isbf) * ldf(mW, (size_t)(l*96 + 64 + k)*64 + c, isbf);
  W[80] = f2bf(fbv);
  for (int k = 81; k < 96; k++) W[k] = 0;
  if (l == 0){
    u16* We = Weff + (size_t)c*96;
    for (int k = 0; k < 96; k++) We[k] = W[k];
    uaff[c] = 1.0f; uaff[64 + c] = 0.0f;     // identity node-BN for layer 0
  }
}

// ---------------- per-layer fold: Weff[lnext] = BN-affine applied to Wcol ----
__global__ void k_fold(const u16* __restrict__ Wcol, u16* __restrict__ Weff,
                       const float* __restrict__ uaff, int lnext){
  int c = threadIdx.x;
  const u16* src = Wcol + ((size_t)lnext*64 + c)*96;
  u16* dst = Weff + ((size_t)lnext*64 + c)*96;
  float bias = bf2f(src[80]);
  for (int k = 0; k < 64; k++){
    float w = bf2f(src[k]);
    dst[k] = f2bf(w * uaff[k]);
    bias = fmaf(uaff[64 + k], w, bias);
  }
  for (int k = 64; k < 80; k++) dst[k] = src[k];
  dst[80] = f2bf(bias);
  for (int k = 81; k < 96; k++) dst[k] = 0;
}

// ---------------- node embedding: h = x @ node_W + node_b (f32 + bf16) ------
__global__ void k_node_emb(const void* __restrict__ x, const void* __restrict__ nW,
                           const void* __restrict__ nb, float* __restrict__ h,
                           u16* __restrict__ h_bf, const int* __restrict__ flagp){
  int isbf = *flagp;
  int lane = threadIdx.x & 63;
  int gw = (blockIdx.x*blockDim.x + threadIdx.x) >> 6;
  int nw = (gridDim.x*blockDim.x) >> 6;
  float w[32];
#pragma unroll
  for (int k = 0; k < 32; k++) w[k] = ldf(nW, (size_t)k*64 + lane, isbf);
  float bias = ldf(nb, lane, isbf);
  for (int n = gw; n < N_NODES; n += nw){
    float acc = bias;
    if (isbf){
      const uint4* xr = (const uint4*)((const u16*)x + (size_t)n*32);
#pragma unroll
      for (int q = 0; q < 4; q++){
        uint4 a = xr[q];
        u32 uu[4] = {a.x, a.y, a.z, a.w};
#pragma unroll
        for (int j = 0; j < 4; j++){
          acc = fmaf(BL(uu[j]), w[q*8 + 2*j + 0], acc);
          acc = fmaf(BH(uu[j]), w[q*8 + 2*j + 1], acc);
        }
      }
    } else {
      const float4* xr = (const float4*)((const float*)x + (size_t)n*32);
#pragma unroll
      for (int q = 0; q < 8; q++){
        float4 a = xr[q];
        acc = fmaf(a.x, w[q*4+0], acc); acc = fmaf(a.y, w[q*4+1], acc);
        acc = fmaf(a.z, w[q*4+2], acc); acc = fmaf(a.w, w[q*4+3], acc);
      }
    }
    h[(size_t)n*64 + lane] = acc;
    h_bf[(size_t)n*64 + lane] = f2bf(acc);
  }
}

// ---------------- in-degree histogram ----------------
__global__ void k_deg(const int* __restrict__ ei, int* __restrict__ deg){
  int i = blockIdx.x*blockDim.x + threadIdx.x;
  int stride = gridDim.x*blockDim.x;
  for (int e = i; e < N_EDGES; e += stride)
    atomicAdd(&deg[ei[N_EDGES + e]], 1);
}

// ---------------- multi-block scan: phase 1 (block sums) ----------------
__global__ void __launch_bounds__(256) k_scan1(const int* __restrict__ deg,
                                               int* __restrict__ bsum){
  __shared__ int wsum[4];
  int b = blockIdx.x, t = threadIdx.x;
  int i0 = b*512 + t;
  int s = 0;
  if (i0 < N_NODES) s += deg[i0];
  if (i0 + 256 < N_NODES) s += deg[i0 + 256];
  for (int o = 32; o; o >>= 1) s += __shfl_xor(s, o);
  if ((t & 63) == 0) wsum[t >> 6] = s;
  __syncthreads();
  if (t == 0) bsum[b] = wsum[0] + wsum[1] + wsum[2] + wsum[3];
}

// ---------------- scan phase 2 ----------------
__global__ void k_scan2(const int* __restrict__ bsum, int* __restrict__ boff,
                        int* __restrict__ rp){
  __shared__ int l[200];
  int t = threadIdx.x;
  if (t < 196) l[t] = bsum[t];
  __syncthreads();
  if (t == 0){
    int r = 0;
    for (int k = 0; k < 196; k++){ int x = l[k]; l[k] = r; r += x; }
    rp[N_NODES] = r;
  }
  __syncthreads();
  if (t < 196) boff[t] = l[t];
}

// ---------------- scan phase 3 ----------------
__global__ void __launch_bounds__(256) k_scan3(const int* __restrict__ deg,
                        const int* __restrict__ boff, int* __restrict__ rp,
                        int* __restrict__ cursor, float* __restrict__ degf){
  __shared__ int wpre[4];
  int b = blockIdx.x, t = threadIdx.x;
  int i0 = b*512 + 2*t;
  int d0 = (i0     < N_NODES) ? deg[i0]     : 0;
  int d1 = (i0 + 1 < N_NODES) ? deg[i0 + 1] : 0;
  int s = d0 + d1;
  int incl = s;
  for (int o = 1; o < 64; o <<= 1){ int u = __shfl_up(incl, o); if ((t & 63) >= o) incl += u; }
  if ((t & 63) == 63) wpre[t >> 6] = incl;
  __syncthreads();
  if (t == 0){ int r = 0; for (int k = 0; k < 4; k++){ int x = wpre[k]; wpre[k] = r; r += x; } }
  __syncthreads();
  int excl = boff[b] + wpre[t >> 6] + incl - s;
  if (i0 < N_NODES){
    rp[i0] = excl; cursor[i0] = excl; degf[i0] = (float)d0;
  }
  if (i0 + 1 < N_NODES){
    rp[i0+1] = excl + d0; cursor[i0+1] = excl + d0; degf[i0+1] = (float)d1;
  }
}

// ---------------- CSR scatter: (src, eid) pairs into dst buckets ----------
__global__ void k_scatter(const int* __restrict__ ei, int* __restrict__ cursor,
                          int* __restrict__ perm2){
  int i = blockIdx.x*blockDim.x + threadIdx.x;
  int stride = gridDim.x*blockDim.x;
  for (int e = i; e < N_EDGES; e += stride){
    int d = ei[N_EDGES + e];
    int p = atomicAdd(&cursor[d], 1);
    ((int2*)perm2)[p] = make_int2(ei[e], e);
  }
}

// ---------------- MFMA message + gather-aggregate + BN stats ----------------
// A-fragments loaded DIRECTLY from global (no LDS): lane(nn,kg) takes the 16B
// slice of h_bf[src]/ea[eid] that IS its mfma_16x16x32 A operand. kb2 holds
// [ea | bias-pad 1.0 | zeros]. One plain 256B store per node; no atomics.
__global__ void __launch_bounds__(256) k_msgmm(
    const u16* __restrict__ h_bf, const void* __restrict__ ea,
    const int* __restrict__ rp, const int* __restrict__ perm2,
    const u16* __restrict__ Weff, float* __restrict__ agg,
    float* __restrict__ stats, const int* __restrict__ flagp,
    int l, int nwaves){
  __shared__ float bs[128];
  int tid = threadIdx.x;
  if (tid < 128) bs[tid] = 0.f;
  __syncthreads();
  int isbf = *flagp;
  int lane = tid & 63, wv = tid >> 6;
  int w = blockIdx.x*4 + wv;
  long long t0 = (long long)w     * N_EDGES / nwaves;
  long long t1 = (long long)(w+1) * N_EDGES / nwaves;
  int lo = 0, hi = N_NODES;
  while (lo < hi){ int mid = (lo+hi)>>1; if ((long long)rp[mid] < t0) lo = mid+1; else hi = mid; }
  int n0 = lo, n1;
  if (w == nwaves-1) n1 = N_NODES;
  else {
    lo = 0; hi = N_NODES;
    while (lo < hi){ int mid = (lo+hi)>>1; if ((long long)rp[mid] < t1) lo = mid+1; else hi = mid; }
    n1 = lo;
  }
  int nn = lane & 15, kg = lane >> 4;
  bf16x8 B[3][4];
  const u16* Wl = Weff + (size_t)l*64*96;
#pragma unroll
  for (int t = 0; t < 4; t++)
#pragma unroll
    for (int kb = 0; kb < 3; kb++)
      B[kb][t] = *(const bf16x8*)(Wl + (size_t)(t*16+nn)*96 + kb*32 + kg*8);
  // constant kb2 fragment for kg>=2: kg==2 -> {1.0bf16,0,...}, kg==3 -> 0
  U4BF ac; ac.u = make_uint4((kg==2)? 0x3f80u : 0u, 0u, 0u, 0u);
  float s1[4] = {0,0,0,0}, s2[4] = {0,0,0,0};
  for (int n = n0; n < n1; n++){
    int b0 = rp[n], b1 = rp[n+1];
    float r0 = 0.f, r1 = 0.f, r2 = 0.f, r3 = 0.f;
    for (int base = b0; base < b1; base += 16){
      int rem = b1 - base; if (rem > 16) rem = 16;
      int row = (nn < rem) ? nn : rem-1;         // clamp: dup last edge, mask later
      int2 p = ((const int2*)perm2)[base + row];
      const uint4* hp = (const uint4*)(h_bf + (size_t)p.x*64);
      U4BF fA, fB, fC;
      fA.u = hp[kg];                              // kb0: h bytes kg*16..+15
      fB.u = hp[4 + kg];                          // kb1: h bytes 64+kg*16..+15
      if (kg < 2){
        if (isbf){
          fC.u = ((const uint4*)ea)[(size_t)p.y*2 + kg];
        } else {
          const float4* ef = (const float4*)ea;
          float4 f0 = ef[(size_t)p.y*4 + kg*2];
          float4 f1 = ef[(size_t)p.y*4 + kg*2 + 1];
          fC.u.x = (u32)f2bf(f0.x) | ((u32)f2bf(f0.y)<<16);
          fC.u.y = (u32)f2bf(f0.z) | ((u32)f2bf(f0.w)<<16);
          fC.u.z = (u32)f2bf(f1.x) | ((u32)f2bf(f1.y)<<16);
          fC.u.w = (u32)f2bf(f1.z) | ((u32)f2bf(f1.w)<<16);
        }
      } else fC = ac;
      f32x4 a0 = {0,0,0,0}, a1 = {0,0,0,0}, a2 = {0,0,0,0}, a3 = {0,0,0,0};
      a0 = __builtin_amdgcn_mfma_f32_16x16x32_bf16(fA.v, B[0][0], a0, 0,0,0);
      a1 = __builtin_amdgcn_mfma_f32_16x16x32_bf16(fA.v, B[0][1], a1, 0,0,0);
      a2 = __builtin_amdgcn_mfma_f32_16x16x32_bf16(fA.v, B[0][2], a2, 0,0,0);
      a3 = __builtin_amdgcn_mfma_f32_16x16x32_bf16(fA.v, B[0][3], a3, 0,0,0);
      a0 = __builtin_amdgcn_mfma_f32_16x16x32_bf16(fB.v, B[1][0], a0, 0,0,0);
      a1 = __builtin_amdgcn_mfma_f32_16x16x32_bf16(fB.v, B[1][1], a1, 0,0,0);
      a2 = __builtin_amdgcn_mfma_f32_16x16x32_bf16(fB.v, B[1][2], a2, 0,0,0);
      a3 = __builtin_amdgcn_mfma_f32_16x16x32_bf16(fB.v, B[1][3], a3, 0,0,0);
      a0 = __builtin_amdgcn_mfma_f32_16x16x32_bf16(fC.v, B[2][0], a0, 0,0,0);
      a1 = __builtin_amdgcn_mfma_f32_16x16x32_bf16(fC.v, B[2][1], a1, 0,0,0);
      a2 = __builtin_amdgcn_mfma_f32_16x16x32_bf16(fC.v, B[2][2], a2, 0,0,0);
      a3 = __builtin_amdgcn_mfma_f32_16x16x32_bf16(fC.v, B[2][3], a3, 0,0,0);
      int rowbase = kg*4;
      float ts0 = 0.f, ts1 = 0.f, ts2 = 0.f, ts3 = 0.f;
#pragma unroll
      for (int j = 0; j < 4; j++){
        bool valid = (rowbase + j) < rem;
        float m0 = fmaxf(a0[j], 0.f); m0 = valid ? m0 : 0.f;
        float m1 = fmaxf(a1[j], 0.f); m1 = valid ? m1 : 0.f;
        float m2 = fmaxf(a2[j], 0.f); m2 = valid ? m2 : 0.f;
        float m3 = fmaxf(a3[j], 0.f); m3 = valid ? m3 : 0.f;
        ts0 += m0; ts1 += m1; ts2 += m2; ts3 += m3;
        s2[0] = fmaf(m0,m0,s2[0]); s2[1] = fmaf(m1,m1,s2[1]);
        s2[2] = fmaf(m2,m2,s2[2]); s2[3] = fmaf(m3,m3,s2[3]);
      }
      s1[0] += ts0; s1[1] += ts1; s1[2] += ts2; s1[3] += ts3;
      ts0 += __shfl_xor(ts0,16); ts0 += __shfl_xor(ts0,32);
      ts1 += __shfl_xor(ts1,16); ts1 += __shfl_xor(ts1,32);
      ts2 += __shfl_xor(ts2,16); ts2 += __shfl_xor(ts2,32);
      ts3 += __shfl_xor(ts3,16); ts3 += __shfl_xor(ts3,32);
      r0 += ts0; r1 += ts1; r2 += ts2; r3 += ts3;
    }
    float v = (kg==0) ? r0 : (kg==1) ? r1 : (kg==2) ? r2 : r3;   // col = lane
    agg[(size_t)n*64 + lane] = v;
  }
#pragma unroll
  for (int t = 0; t < 4; t++){
    atomicAdd(&bs[t*16+nn], s1[t]);
    atomicAdd(&bs[64+t*16+nn], s2[t]);
  }
  __syncthreads();
  if (tid < 128) atomicAdd(&stats[tid], bs[tid]);
}

// ---------------- BN finalize (self-zeroes stats for next layer) ------------
__global__ void k_fin(float* __restrict__ stats, const void* __restrict__ gamma,
                      const void* __restrict__ beta, float* __restrict__ aff,
                      float cnt_inv, int goff, const int* __restrict__ flagp){
  int isbf = *flagp; int c = threadIdx.x;
  float mu  = stats[c]      * cnt_inv;
  float var = stats[64 + c] * cnt_inv - mu*mu;
  float rs  = rsqrtf(var + 1e-5f);
  float g = ldf(gamma, (size_t)goff + c, isbf);
  float b = ldf(beta,  (size_t)goff + c, isbf);
  aff[c]      = g*rs;
  aff[64 + c] = b - g*mu*rs;
  stats[c] = 0.f; stats[64 + c] = 0.f;
}

// ---------------- fused update (pre-BN output; node-BN folded at consumers) -
// wa[k] = Wa[k][c]*s_prev[k]  (+bias += t_prev@Wa), wb[k] = Wb[k][c]*maff_s[k]
__global__ void __launch_bounds__(256) k_upd(
    float* __restrict__ h, u16* __restrict__ h_bf, const float* __restrict__ agg,
    const float* __restrict__ degf, const float* __restrict__ maff,
    const float* __restrict__ aff_prev,
    const void* __restrict__ uW, const void* __restrict__ ub,
    float* __restrict__ stats, const int* __restrict__ flagp, int l){
  __shared__ float bs[128];
  if (threadIdx.x < 128) bs[threadIdx.x] = 0.f;
  __syncthreads();
  int isbf = *flagp;
  int lane = threadIdx.x & 63;
  int gw = (blockIdx.x*blockDim.x + threadIdx.x) >> 6;
  int nw = (gridDim.x*blockDim.x) >> 6;
  float wa[64], wb[64]; float tv = 0.f, tv2 = 0.f;
#pragma unroll
  for (int k = 0; k < 64; k++){
    float wka = ldf(uW, (size_t)(l*128 + k)*64 + lane, isbf);
    wa[k] = wka * aff_prev[k];
    tv2 = fmaf(aff_prev[64 + k], wka, tv2);
    float wk = ldf(uW, (size_t)(l*128 + 64 + k)*64 + lane, isbf);
    wb[k] = wk * maff[k];
    tv = fmaf(maff[64 + k], wk, tv);
  }
  float bias = ldf(ub, (size_t)l*64 + lane, isbf) + tv2;
  float s1 = 0.f, s2 = 0.f;
  for (int n = gw; n < N_NODES; n += nw){
    const float4* hr = (const float4*)(h + (size_t)n*64);
    const float4* ar = (const float4*)(agg + (size_t)n*64);
    float a0 = fmaf(degf[n], tv, bias), a1 = 0.f, a2 = 0.f, a3 = 0.f;
#pragma unroll
    for (int q = 0; q < 8; q++){
      float4 a = hr[2*q+0];
      a0 = fmaf(a.x, wa[8*q+0], a0); a0 = fmaf(a.y, wa[8*q+1], a0);
      a0 = fmaf(a.z, wa[8*q+2], a0); a0 = fmaf(a.w, wa[8*q+3], a0);
      float4 b = hr[2*q+1];
      a1 = fmaf(b.x, wa[8*q+4], a1); a1 = fmaf(b.y, wa[8*q+5], a1);
      a1 = fmaf(b.z, wa[8*q+6], a1); a1 = fmaf(b.w, wa[8*q+7], a1);
      float4 c = ar[2*q+0];
      a2 = fmaf(c.x, wb[8*q+0], a2); a2 = fmaf(c.y, wb[8*q+1], a2);
      a2 = fmaf(c.z, wb[8*q+2], a2); a2 = fmaf(c.w, wb[8*q+3], a2);
      float4 d = ar[2*q+1];
      a3 = fmaf(d.x, wb[8*q+4], a3); a3 = fmaf(d.y, wb[8*q+5], a3);
      a3 = fmaf(d.z, wb[8*q+6], a3); a3 = fmaf(d.w, wb[8*q+7], a3);
    }
    float rl = fmaxf((a0 + a1) + (a2 + a3), 0.f);
    h[(size_t)n*64 + lane] = rl;
    h_bf[(size_t)n*64 + lane] = f2bf(rl);
    s1 += rl;
    s2 = fmaf(rl, rl, s2);
  }
  atomicAdd(&bs[lane], s1);
  atomicAdd(&bs[64 + lane], s2);
  __syncthreads();
  if (threadIdx.x < 128) atomicAdd(&stats[threadIdx.x], bs[threadIdx.x]);
}

// ---------------- global add pool (applies final node-BN affine inline) -----
__global__ void k_pool(const float* __restrict__ h, const int* __restrict__ batch,
                       const float* __restrict__ uaff, float* __restrict__ g){
  int lane = threadIdx.x & 63;
  int gw = (blockIdx.x*blockDim.x + threadIdx.x) >> 6;
  int nw = (gridDim.x*blockDim.x) >> 6;
  float s = uaff[lane], t = uaff[64 + lane];
  int chunk = (N_NODES + nw - 1) / nw;
  int n0 = gw*chunk;
  int n1 = n0 + chunk; if (n1 > N_NODES) n1 = N_NODES;
  int cur = -1; float acc = 0.f;
  for (int n = n0; n < n1; n++){
    int b = batch[n];
    float v = fmaf(s, h[(size_t)n*64 + lane], t);
    if (b != cur){
      if (cur >= 0) atomicAdd(&g[(size_t)cur*64 + lane], acc);
      cur = b; acc = v;
    } else acc += v;
  }
  if (cur >= 0) atomicAdd(&g[(size_t)cur*64 + lane], acc);
}

// ---------------- readout ----------------
__global__ void k_read(const float* __restrict__ g, const void* __restrict__ r1W,
                       const void* __restrict__ r1b, const void* __restrict__ r2W,
                       const void* __restrict__ r2b, void* __restrict__ out,
                       const int* __restrict__ flagp){
  int isbf = *flagp;
  int lane = threadIdx.x;
  int gr = blockIdx.x;
  float w[64];
#pragma unroll
  for (int k = 0; k < 64; k++) w[k] = ldf(r1W, (size_t)k*64 + lane, isbf);
  float acc = ldf(r1b, lane, isbf);
  const float4* grow = (const float4*)(g + (size_t)gr*64);
#pragma unroll
  for (int q = 0; q < 16; q++){
    float4 a = grow[q];
    acc = fmaf(a.x, w[4*q+0], acc); acc = fmaf(a.y, w[4*q+1], acc);
    acc = fmaf(a.z, w[4*q+2], acc); acc = fmaf(a.w, w[4*q+3], acc);
  }
  float hid = fmaxf(acc, 0.f);
  float p = hid * ldf(r2W, lane, isbf);
  for (int o = 32; o; o >>= 1) p += __shfl_xor(p, o);
  if (lane == 0){
    float v = p + ldf(r2b, 0, isbf);
    if (isbf) ((__hip_bfloat16*)out)[gr] = __float2bfloat16(v);
    else      ((float*)out)[gr] = v;
  }
}

extern "C" void kernel_launch(void* const* d_in, const int* in_sizes, int n_in,
                              void* d_out, int out_size, void* d_ws, size_t ws_size,
                              hipStream_t stream){
  const void* x    = d_in[0];
  const void* ea   = d_in[1];
  const int*  ei   = (const int*)d_in[2];
  const int*  bt   = (const int*)d_in[3];
  const void* nW   = d_in[4];  const void* nb  = d_in[5];
  const void* eW   = d_in[6];  const void* eb  = d_in[7];
  const void* mW   = d_in[8];  const void* mb  = d_in[9];
  const void* mg   = d_in[10]; const void* mbe = d_in[11];
  const void* uW   = d_in[12]; const void* ub  = d_in[13];
  const void* ug   = d_in[14]; const void* ube = d_in[15];
  const void* r1W  = d_in[16]; const void* r1b = d_in[17];
  const void* r2W  = d_in[18]; const void* r2b = d_in[19];

  float* ws = (float*)d_ws;
  float* h        = ws + 0;                   // 6,400,000
  float* agg      = ws + 6400000;             // 6,400,000
  u16*   h_bf     = (u16*)(ws + 12800000);    // 3,200,000 fl
  int*   perm2    = (int*)(ws + 16000000);    // 3,200,000 ints (1.6M int2)
  float* degf     = ws + 19200000;            //   100,000
  int*   deg_i    = (int*)(ws + 19300000);    //   100,000  -- memset start
  float* g        = ws + 19400000;            //    64,000
  float* mstats   = ws + 19464000;            //       128
  float* ustats   = ws + 19464128;            //       128  -- memset end (164,256 fl)
  float* maff     = ws + 19464256;            //       128
  float* uaff     = ws + 19464384;            //       128
  int*   flag     = (int*)(ws + 19464512);    //        16
  u16*   Wcol     = (u16*)(ws + 19464528);    //     9,216 fl (orig)
  u16*   Weff     = (u16*)(ws + 19473744);    //     9,216 fl (BN-folded)
  int*   row_ptr  = (int*)(ws + 19482960);    //   100,001
  int*   cursor   = (int*)(ws + 19582964);    //   100,000
  int*   bsum     = (int*)(ws + 19682964);    //       196
  int*   boff     = (int*)(ws + 19683160);    //       196 -> end 19,683,356 fl

  const int MM_BLOCKS = 2048;
  const int MM_WAVES  = MM_BLOCKS * 4;

  k_detect<<<1, 64, 0, stream>>>((const u32*)x, flag);
  hipMemsetAsync(ws + 19300000, 0, 164256*sizeof(float), stream); // deg_i+g+stats
  k_prep<<<3, 64, 0, stream>>>(eW, eb, mW, mb, Wcol, Weff, uaff, flag);
  k_node_emb<<<256, 256, 0, stream>>>(x, nW, nb, h, h_bf, flag);
  k_deg<<<512, 256, 0, stream>>>(ei, deg_i);
  k_scan1<<<196, 256, 0, stream>>>(deg_i, bsum);
  k_scan2<<<1, 256, 0, stream>>>(bsum, boff, row_ptr);
  k_scan3<<<196, 256, 0, stream>>>(deg_i, boff, row_ptr, cursor, degf);
  k_scatter<<<512, 256, 0, stream>>>(ei, cursor, perm2);

  for (int l = 0; l < 3; l++){
    k_msgmm<<<MM_BLOCKS, 256, 0, stream>>>(h_bf, ea, row_ptr, perm2, Weff,
                                           agg, mstats, flag, l, MM_WAVES);
    k_fin<<<1, 64, 0, stream>>>(mstats, mg, mbe, maff, 1.0f/(float)N_EDGES, l*64, flag);
    k_upd<<<1024, 256, 0, stream>>>(h, h_bf, agg, degf, maff, uaff, uW, ub,
                                    ustats, flag, l);
    k_fin<<<1, 64, 0, stream>>>(ustats, ug, ube, uaff, 1.0f/(float)N_NODES, l*64, flag);
    if (l < 2) k_fold<<<1, 64, 0, stream>>>(Wcol, Weff, uaff, l+1);
  }

  k_pool<<<128, 256, 0, stream>>>(h, bt, uaff, g);
  k_read<<<NUM_GRAPHS, 64, 0, stream>>>(g, r1W, r1b, r2W, r2b, d_out, flag);
}

// Round 7
// 1455.163 us; speedup vs baseline: 1.0868x; 1.0868x over previous
//
#include <hip/hip_runtime.h>
#include <hip/hip_bf16.h>

#define N_NODES   100000
#define N_EDGES   1600000
#define NUM_GRAPHS 1000

typedef unsigned int u32;
typedef unsigned short u16;

typedef __bf16 bf16_t;
typedef bf16_t bf16x8 __attribute__((ext_vector_type(8)));
typedef float  f32x4  __attribute__((ext_vector_type(4)));

__device__ __forceinline__ float bf2f(u16 u){ return __uint_as_float(((u32)u)<<16); }
__device__ __forceinline__ float BL(u32 u){ return __uint_as_float(u<<16); }
__device__ __forceinline__ float BH(u32 u){ return __uint_as_float(u&0xffff0000u); }
// f32 -> bf16 bits, round-to-nearest-even
__device__ __forceinline__ u16 f2bf(float f){
  u32 u = __float_as_uint(f);
  return (u16)((u + 0x7fffu + ((u>>16)&1u)) >> 16);
}
// dual-dtype scalar load: isbf=1 -> bf16, else f32
__device__ __forceinline__ float ldf(const void* p, size_t i, int isbf){
  return isbf ? bf2f(((const u16*)p)[i]) : ((const float*)p)[i];
}

union U4BF { uint4 u; bf16x8 v; };

// ---------------- dtype detector ----------------
__global__ void k_detect(const u32* __restrict__ x, int* __restrict__ flag){
  int t = threadIdx.x; int cnt = 0;
  for (int i = t; i < 256; i += 64){
    u32 w = x[i];
    u32 e = (w >> 7) & 0xffu;
    if (e >= 110u && e <= 137u) cnt++;
  }
  for (int o = 32; o; o >>= 1) cnt += __shfl_xor(cnt, o);
  if (t == 0) *flag = (cnt > 128) ? 1 : 0;
}

// ---------------- weight prep: bf16 Weff[l][c][96] for ALL layers ----------
// (h is stored post-BN, so no per-layer refold needed.)
// k 0..63 msg_W1 | 64..79 folded edge emb | 80 folded bias (A pad col=1.0) | 81..95 zero
__global__ void k_prep(const void* __restrict__ eW, const void* __restrict__ eb,
                       const void* __restrict__ mW, const void* __restrict__ mb,
                       u16* __restrict__ Weff, const int* __restrict__ flagp){
  int isbf = *flagp;
  int l = blockIdx.x, c = threadIdx.x;
  u16* W = Weff + ((size_t)l*64 + c)*96;
  for (int k = 0; k < 64; k++)
    W[k] = f2bf(ldf(mW, (size_t)(l*96 + k)*64 + c, isbf));
  for (int j = 0; j < 16; j++){
    float acc = 0.f;
    for (int k = 0; k < 32; k++)
      acc += ldf(eW, (size_t)j*32 + k, isbf) * ldf(mW, (size_t)(l*96 + 64 + k)*64 + c, isbf);
    W[64 + j] = f2bf(acc);
  }
  float fbv = ldf(mb, (size_t)l*64 + c, isbf);
  for (int k = 0; k < 32; k++)
    fbv += ldf(eb, k, isbf) * ldf(mW, (size_t)(l*96 + 64 + k)*64 + c, isbf);
  W[80] = f2bf(fbv);
  for (int k = 81; k < 96; k++) W[k] = 0;
}

// ---------------- update-weight prep: Wupd[c][192] bf16 + f32 tables --------
// blocks 0,1: Wa native (h is post-BN so Wa needs NO fold);
// blocks 2,3: hi(Wb*maff_s); blocks 4,5: lo residual of same.
// biasv[c] = ub[c]; tvv[c] = maff_t @ Wb[.][c]
__global__ void k_updprep(const void* __restrict__ uW, const void* __restrict__ ub,
                          const float* __restrict__ maff,
                          u16* __restrict__ Wupd, float* __restrict__ biasv,
                          float* __restrict__ tvv, const int* __restrict__ flagp, int l){
  int isbf = *flagp; int c = threadIdx.x;
  u16* W = Wupd + (size_t)c*192;
  float tv = 0.f;
  for (int k = 0; k < 64; k++){
    float wka = ldf(uW, (size_t)(l*128 + k)*64 + c, isbf);
    W[k] = f2bf(wka);
    float wkb = ldf(uW, (size_t)(l*128 + 64 + k)*64 + c, isbf);
    float prod = wkb * maff[k];
    u16 hi = f2bf(prod);
    W[64 + k]  = hi;
    W[128 + k] = f2bf(prod - bf2f(hi));
    tv = fmaf(maff[64 + k], wkb, tv);
  }
  biasv[c] = ldf(ub, (size_t)l*64 + c, isbf);
  tvv[c] = tv;
}

// ---------------- node embedding -> hsp split hi/lo (row stride 128 u16) ----
__global__ void k_node_emb(const void* __restrict__ x, const void* __restrict__ nW,
                           const void* __restrict__ nb, u16* __restrict__ hsp,
                           const int* __restrict__ flagp){
  int isbf = *flagp;
  int lane = threadIdx.x & 63;
  int gw = (blockIdx.x*blockDim.x + threadIdx.x) >> 6;
  int nw = (gridDim.x*blockDim.x) >> 6;
  float w[32];
#pragma unroll
  for (int k = 0; k < 32; k++) w[k] = ldf(nW, (size_t)k*64 + lane, isbf);
  float bias = ldf(nb, lane, isbf);
  for (int n = gw; n < N_NODES; n += nw){
    float acc = bias;
    if (isbf){
      const uint4* xr = (const uint4*)((const u16*)x + (size_t)n*32);
#pragma unroll
      for (int q = 0; q < 4; q++){
        uint4 a = xr[q];
        u32 uu[4] = {a.x, a.y, a.z, a.w};
#pragma unroll
        for (int j = 0; j < 4; j++){
          acc = fmaf(BL(uu[j]), w[q*8 + 2*j + 0], acc);
          acc = fmaf(BH(uu[j]), w[q*8 + 2*j + 1], acc);
        }
      }
    } else {
      const float4* xr = (const float4*)((const float*)x + (size_t)n*32);
#pragma unroll
      for (int q = 0; q < 8; q++){
        float4 a = xr[q];
        acc = fmaf(a.x, w[q*4+0], acc); acc = fmaf(a.y, w[q*4+1], acc);
        acc = fmaf(a.z, w[q*4+2], acc); acc = fmaf(a.w, w[q*4+3], acc);
      }
    }
    u16 hi = f2bf(acc);
    hsp[(size_t)n*128 + lane]      = hi;
    hsp[(size_t)n*128 + 64 + lane] = f2bf(acc - bf2f(hi));
  }
}

// ---------------- in-degree histogram ----------------
__global__ void k_deg(const int* __restrict__ ei, int* __restrict__ deg){
  int i = blockIdx.x*blockDim.x + threadIdx.x;
  int stride = gridDim.x*blockDim.x;
  for (int e = i; e < N_EDGES; e += stride)
    atomicAdd(&deg[ei[N_EDGES + e]], 1);
}

// ---------------- multi-block scan: phase 1 ----------------
__global__ void __launch_bounds__(256) k_scan1(const int* __restrict__ deg,
                                               int* __restrict__ bsum){
  __shared__ int wsum[4];
  int b = blockIdx.x, t = threadIdx.x;
  int i0 = b*512 + t;
  int s = 0;
  if (i0 < N_NODES) s += deg[i0];
  if (i0 + 256 < N_NODES) s += deg[i0 + 256];
  for (int o = 32; o; o >>= 1) s += __shfl_xor(s, o);
  if ((t & 63) == 0) wsum[t >> 6] = s;
  __syncthreads();
  if (t == 0) bsum[b] = wsum[0] + wsum[1] + wsum[2] + wsum[3];
}

// ---------------- scan phase 2 ----------------
__global__ void k_scan2(const int* __restrict__ bsum, int* __restrict__ boff,
                        int* __restrict__ rp){
  __shared__ int l[200];
  int t = threadIdx.x;
  if (t < 196) l[t] = bsum[t];
  __syncthreads();
  if (t == 0){
    int r = 0;
    for (int k = 0; k < 196; k++){ int x = l[k]; l[k] = r; r += x; }
    rp[N_NODES] = r;
  }
  __syncthreads();
  if (t < 196) boff[t] = l[t];
}

// ---------------- scan phase 3 ----------------
__global__ void __launch_bounds__(256) k_scan3(const int* __restrict__ deg,
                        const int* __restrict__ boff, int* __restrict__ rp,
                        int* __restrict__ cursor, float* __restrict__ degf){
  __shared__ int wpre[4];
  int b = blockIdx.x, t = threadIdx.x;
  int i0 = b*512 + 2*t;
  int d0 = (i0     < N_NODES) ? deg[i0]     : 0;
  int d1 = (i0 + 1 < N_NODES) ? deg[i0 + 1] : 0;
  int s = d0 + d1;
  int incl = s;
  for (int o = 1; o < 64; o <<= 1){ int u = __shfl_up(incl, o); if ((t & 63) >= o) incl += u; }
  if ((t & 63) == 63) wpre[t >> 6] = incl;
  __syncthreads();
  if (t == 0){ int r = 0; for (int k = 0; k < 4; k++){ int x = wpre[k]; wpre[k] = r; r += x; } }
  __syncthreads();
  int excl = boff[b] + wpre[t >> 6] + incl - s;
  if (i0 < N_NODES){
    rp[i0] = excl; cursor[i0] = excl; degf[i0] = (float)d0;
  }
  if (i0 + 1 < N_NODES){
    rp[i0+1] = excl + d0; cursor[i0+1] = excl + d0; degf[i0+1] = (float)d1;
  }
}

// ---------------- CSR scatter ----------------
__global__ void k_scatter(const int* __restrict__ ei, int* __restrict__ cursor,
                          int* __restrict__ perm2){
  int i = blockIdx.x*blockDim.x + threadIdx.x;
  int stride = gridDim.x*blockDim.x;
  for (int e = i; e < N_EDGES; e += stride){
    int d = ei[N_EDGES + e];
    int p = atomicAdd(&cursor[d], 1);
    ((int2*)perm2)[p] = make_int2(ei[e], e);
  }
}

// ---------------- MFMA message + gather-aggregate + BN stats ----------------
// h input: hsp hi-half (post-BN, bf16 — same as round-5 numerics).
// agg output: split hi/lo into aggs (row stride 128 u16).
__global__ void __launch_bounds__(256) k_msgmm(
    const u16* __restrict__ hsp, const void* __restrict__ ea,
    const int* __restrict__ rp, const int* __restrict__ perm2,
    const u16* __restrict__ Weff, u16* __restrict__ aggs,
    float* __restrict__ stats, const int* __restrict__ flagp,
    int l, int nwaves){
  __shared__ float bs[128];
  int tid = threadIdx.x;
  if (tid < 128) bs[tid] = 0.f;
  __syncthreads();
  int isbf = *flagp;
  int lane = tid & 63, wv = tid >> 6;
  int w = blockIdx.x*4 + wv;
  long long t0 = (long long)w     * N_EDGES / nwaves;
  long long t1 = (long long)(w+1) * N_EDGES / nwaves;
  int lo = 0, hi = N_NODES;
  while (lo < hi){ int mid = (lo+hi)>>1; if ((long long)rp[mid] < t0) lo = mid+1; else hi = mid; }
  int n0 = lo, n1;
  if (w == nwaves-1) n1 = N_NODES;
  else {
    lo = 0; hi = N_NODES;
    while (lo < hi){ int mid = (lo+hi)>>1; if ((long long)rp[mid] < t1) lo = mid+1; else hi = mid; }
    n1 = lo;
  }
  int nn = lane & 15, kg = lane >> 4;
  bf16x8 B[3][4];
  const u16* Wl = Weff + (size_t)l*64*96;
#pragma unroll
  for (int t = 0; t < 4; t++)
#pragma unroll
    for (int kb = 0; kb < 3; kb++)
      B[kb][t] = *(const bf16x8*)(Wl + (size_t)(t*16+nn)*96 + kb*32 + kg*8);
  U4BF ac; ac.u = make_uint4((kg==2)? 0x3f80u : 0u, 0u, 0u, 0u);
  float s1[4] = {0,0,0,0}, s2[4] = {0,0,0,0};
  for (int n = n0; n < n1; n++){
    int b0 = rp[n], b1 = rp[n+1];
    float r0 = 0.f, r1 = 0.f, r2 = 0.f, r3 = 0.f;
    for (int base = b0; base < b1; base += 16){
      int rem = b1 - base; if (rem > 16) rem = 16;
      int row = (nn < rem) ? nn : rem-1;         // clamp: dup last edge, mask later
      int2 p = ((const int2*)perm2)[base + row];
      const uint4* hp = (const uint4*)(hsp + (size_t)p.x*128);
      U4BF fA, fB, fC;
      fA.u = hp[kg];
      fB.u = hp[4 + kg];
      if (kg < 2){
        if (isbf){
          fC.u = ((const uint4*)ea)[(size_t)p.y*2 + kg];
        } else {
          const float4* ef = (const float4*)ea;
          float4 f0 = ef[(size_t)p.y*4 + kg*2];
          float4 f1 = ef[(size_t)p.y*4 + kg*2 + 1];
          fC.u.x = (u32)f2bf(f0.x) | ((u32)f2bf(f0.y)<<16);
          fC.u.y = (u32)f2bf(f0.z) | ((u32)f2bf(f0.w)<<16);
          fC.u.z = (u32)f2bf(f1.x) | ((u32)f2bf(f1.y)<<16);
          fC.u.w = (u32)f2bf(f1.z) | ((u32)f2bf(f1.w)<<16);
        }
      } else fC = ac;
      f32x4 a0 = {0,0,0,0}, a1 = {0,0,0,0}, a2 = {0,0,0,0}, a3 = {0,0,0,0};
      a0 = __builtin_amdgcn_mfma_f32_16x16x32_bf16(fA.v, B[0][0], a0, 0,0,0);
      a1 = __builtin_amdgcn_mfma_f32_16x16x32_bf16(fA.v, B[0][1], a1, 0,0,0);
      a2 = __builtin_amdgcn_mfma_f32_16x16x32_bf16(fA.v, B[0][2], a2, 0,0,0);
      a3 = __builtin_amdgcn_mfma_f32_16x16x32_bf16(fA.v, B[0][3], a3, 0,0,0);
      a0 = __builtin_amdgcn_mfma_f32_16x16x32_bf16(fB.v, B[1][0], a0, 0,0,0);
      a1 = __builtin_amdgcn_mfma_f32_16x16x32_bf16(fB.v, B[1][1], a1, 0,0,0);
      a2 = __builtin_amdgcn_mfma_f32_16x16x32_bf16(fB.v, B[1][2], a2, 0,0,0);
      a3 = __builtin_amdgcn_mfma_f32_16x16x32_bf16(fB.v, B[1][3], a3, 0,0,0);
      a0 = __builtin_amdgcn_mfma_f32_16x16x32_bf16(fC.v, B[2][0], a0, 0,0,0);
      a1 = __builtin_amdgcn_mfma_f32_16x16x32_bf16(fC.v, B[2][1], a1, 0,0,0);
      a2 = __builtin_amdgcn_mfma_f32_16x16x32_bf16(fC.v, B[2][2], a2, 0,0,0);
      a3 = __builtin_amdgcn_mfma_f32_16x16x32_bf16(fC.v, B[2][3], a3, 0,0,0);
      int rowbase = kg*4;
      float ts0 = 0.f, ts1 = 0.f, ts2 = 0.f, ts3 = 0.f;
#pragma unroll
      for (int j = 0; j < 4; j++){
        bool valid = (rowbase + j) < rem;
        float m0 = fmaxf(a0[j], 0.f); m0 = valid ? m0 : 0.f;
        float m1 = fmaxf(a1[j], 0.f); m1 = valid ? m1 : 0.f;
        float m2 = fmaxf(a2[j], 0.f); m2 = valid ? m2 : 0.f;
        float m3 = fmaxf(a3[j], 0.f); m3 = valid ? m3 : 0.f;
        ts0 += m0; ts1 += m1; ts2 += m2; ts3 += m3;
        s2[0] = fmaf(m0,m0,s2[0]); s2[1] = fmaf(m1,m1,s2[1]);
        s2[2] = fmaf(m2,m2,s2[2]); s2[3] = fmaf(m3,m3,s2[3]);
      }
      s1[0] += ts0; s1[1] += ts1; s1[2] += ts2; s1[3] += ts3;
      ts0 += __shfl_xor(ts0,16); ts0 += __shfl_xor(ts0,32);
      ts1 += __shfl_xor(ts1,16); ts1 += __shfl_xor(ts1,32);
      ts2 += __shfl_xor(ts2,16); ts2 += __shfl_xor(ts2,32);
      ts3 += __shfl_xor(ts3,16); ts3 += __shfl_xor(ts3,32);
      r0 += ts0; r1 += ts1; r2 += ts2; r3 += ts3;
    }
    float v = (kg==0) ? r0 : (kg==1) ? r1 : (kg==2) ? r2 : r3;   // col = lane
    u16 hiv = f2bf(v);
    aggs[(size_t)n*128 + lane]      = hiv;
    aggs[(size_t)n*128 + 64 + lane] = f2bf(v - bf2f(hiv));
  }
#pragma unroll
  for (int t = 0; t < 4; t++){
    atomicAdd(&bs[t*16+nn], s1[t]);
    atomicAdd(&bs[64+t*16+nn], s2[t]);
  }
  __syncthreads();
  if (tid < 128) atomicAdd(&stats[tid], bs[tid]);
}

// ---------------- BN finalize (self-zeroes stats) ----------------
__global__ void k_fin(float* __restrict__ stats, const void* __restrict__ gamma,
                      const void* __restrict__ beta, float* __restrict__ aff,
                      float cnt_inv, int goff, const int* __restrict__ flagp){
  int isbf = *flagp; int c = threadIdx.x;
  float mu  = stats[c]      * cnt_inv;
  float var = stats[64 + c] * cnt_inv - mu*mu;
  float rs  = rsqrtf(var + 1e-5f);
  float g = ldf(gamma, (size_t)goff + c, isbf);
  float b = ldf(beta,  (size_t)goff + c, isbf);
  aff[c]      = g*rs;
  aff[64 + c] = b - g*mu*rs;
  stats[c] = 0.f; stats[64 + c] = 0.f;
}

// ---------------- MFMA fused update, split-precision ----------------
// u = h@Wa (hi+lo vs native Wa) + agg@(Wb*maff_s) (hi/lo x hi/lo, lo*lo dropped)
//   + deg*tvv + biasv.  relu -> stats -> write pre-BN split hi/lo IN PLACE
// over aggs (wave owns its 16 rows exclusively).
#define UPD_TILES (N_NODES/16)
__global__ void __launch_bounds__(256) k_updmm(
    const u16* __restrict__ hsp, u16* __restrict__ aggs,
    const float* __restrict__ degf, const u16* __restrict__ Wupd,
    const float* __restrict__ biasv, const float* __restrict__ tvv,
    float* __restrict__ stats){
  __shared__ float bs[128];
  int tid = threadIdx.x;
  if (tid < 128) bs[tid] = 0.f;
  __syncthreads();
  int lane = tid & 63;
  int nn = lane & 15, kg = lane >> 4;
  int w = blockIdx.x*4 + (tid >> 6);
  int nwv = gridDim.x*4;
  bf16x8 B[6][4];
#pragma unroll
  for (int t = 0; t < 4; t++)
#pragma unroll
    for (int kb = 0; kb < 6; kb++)
      B[kb][t] = *(const bf16x8*)(Wupd + (size_t)(t*16+nn)*192 + kb*32 + kg*8);
  float bc[4], tc[4];
#pragma unroll
  for (int t = 0; t < 4; t++){ bc[t] = biasv[t*16+nn]; tc[t] = tvv[t*16+nn]; }
  float s1[4] = {0,0,0,0}, s2[4] = {0,0,0,0};
  for (int tile = w; tile < UPD_TILES; tile += nwv){
    int n0 = tile*16;
    int r = n0 + nn;
    const uint4* hp = (const uint4*)hsp;
    const uint4* ap = (const uint4*)aggs;
    U4BF hh0, hh1, hl0, hl1, ah0, ah1, al0, al1;
    hh0.u = hp[(size_t)r*16 + kg];       hh1.u = hp[(size_t)r*16 + 4 + kg];
    hl0.u = hp[(size_t)r*16 + 8 + kg];   hl1.u = hp[(size_t)r*16 + 12 + kg];
    ah0.u = ap[(size_t)r*16 + kg];       ah1.u = ap[(size_t)r*16 + 4 + kg];
    al0.u = ap[(size_t)r*16 + 8 + kg];   al1.u = ap[(size_t)r*16 + 12 + kg];
    float dg[4];
#pragma unroll
    for (int j = 0; j < 4; j++) dg[j] = degf[n0 + kg*4 + j];
    f32x4 a0 = {0,0,0,0}, a1 = {0,0,0,0}, a2 = {0,0,0,0}, a3 = {0,0,0,0};
#define MF(F,KB) \
    a0 = __builtin_amdgcn_mfma_f32_16x16x32_bf16(F.v, B[KB][0], a0, 0,0,0); \
    a1 = __builtin_amdgcn_mfma_f32_16x16x32_bf16(F.v, B[KB][1], a1, 0,0,0); \
    a2 = __builtin_amdgcn_mfma_f32_16x16x32_bf16(F.v, B[KB][2], a2, 0,0,0); \
    a3 = __builtin_amdgcn_mfma_f32_16x16x32_bf16(F.v, B[KB][3], a3, 0,0,0);
    MF(hh0,0) MF(hh1,1) MF(hl0,0) MF(hl1,1)
    MF(ah0,2) MF(ah1,3) MF(ah0,4) MF(ah1,5)
    MF(al0,2) MF(al1,3)
#undef MF
#pragma unroll
    for (int j = 0; j < 4; j++){
      int n = n0 + kg*4 + j;
      float m0 = fmaxf(fmaf(tc[0], dg[j], a0[j] + bc[0]), 0.f);
      float m1 = fmaxf(fmaf(tc[1], dg[j], a1[j] + bc[1]), 0.f);
      float m2 = fmaxf(fmaf(tc[2], dg[j], a2[j] + bc[2]), 0.f);
      float m3 = fmaxf(fmaf(tc[3], dg[j], a3[j] + bc[3]), 0.f);
      s1[0] += m0; s1[1] += m1; s1[2] += m2; s1[3] += m3;
      s2[0] = fmaf(m0,m0,s2[0]); s2[1] = fmaf(m1,m1,s2[1]);
      s2[2] = fmaf(m2,m2,s2[2]); s2[3] = fmaf(m3,m3,s2[3]);
      u16* hw = aggs + (size_t)n*128;         // pre-BN split, overwrites agg
      u16 q0 = f2bf(m0), q1 = f2bf(m1), q2 = f2bf(m2), q3 = f2bf(m3);
      hw[     nn] = q0;  hw[64 +      nn] = f2bf(m0 - bf2f(q0));
      hw[16 + nn] = q1;  hw[64 + 16 + nn] = f2bf(m1 - bf2f(q1));
      hw[32 + nn] = q2;  hw[64 + 32 + nn] = f2bf(m2 - bf2f(q2));
      hw[48 + nn] = q3;  hw[64 + 48 + nn] = f2bf(m3 - bf2f(q3));
    }
  }
#pragma unroll
  for (int t = 0; t < 4; t++){
    atomicAdd(&bs[t*16+nn], s1[t]);
    atomicAdd(&bs[64+t*16+nn], s2[t]);
  }
  __syncthreads();
  if (tid < 128) atomicAdd(&stats[tid], bs[tid]);
}

// ---------------- node BN apply: hsp = aff(pre-BN in aggs), split hi/lo -----
__global__ void k_norm(const u16* __restrict__ aggs, const float* __restrict__ uaff,
                       u16* __restrict__ hsp){
  int lane = threadIdx.x & 63;
  int gw = (blockIdx.x*blockDim.x + threadIdx.x) >> 6;
  int nw = (gridDim.x*blockDim.x) >> 6;
  float s = uaff[lane], t = uaff[64 + lane];
  for (int n = gw; n < N_NODES; n += nw){
    float v = bf2f(aggs[(size_t)n*128 + lane]) + bf2f(aggs[(size_t)n*128 + 64 + lane]);
    float o = fmaf(s, v, t);
    u16 hi = f2bf(o);
    hsp[(size_t)n*128 + lane]      = hi;
    hsp[(size_t)n*128 + 64 + lane] = f2bf(o - bf2f(hi));
  }
}

// ---------------- global add pool (h already post-BN) ----------------
__global__ void k_pool(const u16* __restrict__ hsp, const int* __restrict__ batch,
                       float* __restrict__ g){
  int lane = threadIdx.x & 63;
  int gw = (blockIdx.x*blockDim.x + threadIdx.x) >> 6;
  int nw = (gridDim.x*blockDim.x) >> 6;
  int chunk = (N_NODES + nw - 1) / nw;
  int n0 = gw*chunk;
  int n1 = n0 + chunk; if (n1 > N_NODES) n1 = N_NODES;
  int cur = -1; float acc = 0.f;
  for (int n = n0; n < n1; n++){
    int b = batch[n];
    float v = bf2f(hsp[(size_t)n*128 + lane]) + bf2f(hsp[(size_t)n*128 + 64 + lane]);
    if (b != cur){
      if (cur >= 0) atomicAdd(&g[(size_t)cur*64 + lane], acc);
      cur = b; acc = v;
    } else acc += v;
  }
  if (cur >= 0) atomicAdd(&g[(size_t)cur*64 + lane], acc);
}

// ---------------- readout ----------------
__global__ void k_read(const float* __restrict__ g, const void* __restrict__ r1W,
                       const void* __restrict__ r1b, const void* __restrict__ r2W,
                       const void* __restrict__ r2b, void* __restrict__ out,
                       const int* __restrict__ flagp){
  int isbf = *flagp;
  int lane = threadIdx.x;
  int gr = blockIdx.x;
  float w[64];
#pragma unroll
  for (int k = 0; k < 64; k++) w[k] = ldf(r1W, (size_t)k*64 + lane, isbf);
  float acc = ldf(r1b, lane, isbf);
  const float4* grow = (const float4*)(g + (size_t)gr*64);
#pragma unroll
  for (int q = 0; q < 16; q++){
    float4 a = grow[q];
    acc = fmaf(a.x, w[4*q+0], acc); acc = fmaf(a.y, w[4*q+1], acc);
    acc = fmaf(a.z, w[4*q+2], acc); acc = fmaf(a.w, w[4*q+3], acc);
  }
  float hid = fmaxf(acc, 0.f);
  float p = hid * ldf(r2W, lane, isbf);
  for (int o = 32; o; o >>= 1) p += __shfl_xor(p, o);
  if (lane == 0){
    float v = p + ldf(r2b, 0, isbf);
    if (isbf) ((__hip_bfloat16*)out)[gr] = __float2bfloat16(v);
    else      ((float*)out)[gr] = v;
  }
}

extern "C" void kernel_launch(void* const* d_in, const int* in_sizes, int n_in,
                              void* d_out, int out_size, void* d_ws, size_t ws_size,
                              hipStream_t stream){
  const void* x    = d_in[0];
  const void* ea   = d_in[1];
  const int*  ei   = (const int*)d_in[2];
  const int*  bt   = (const int*)d_in[3];
  const void* nW   = d_in[4];  const void* nb  = d_in[5];
  const void* eW   = d_in[6];  const void* eb  = d_in[7];
  const void* mW   = d_in[8];  const void* mb  = d_in[9];
  const void* mg   = d_in[10]; const void* mbe = d_in[11];
  const void* uW   = d_in[12]; const void* ub  = d_in[13];
  const void* ug   = d_in[14]; const void* ube = d_in[15];
  const void* r1W  = d_in[16]; const void* r1b = d_in[17];
  const void* r2W  = d_in[18]; const void* r2b = d_in[19];

  float* ws = (float*)d_ws;
  u16*   hsp      = (u16*)(ws + 0);           // 100K*128 u16 = 6,400,000 fl
  u16*   aggs     = (u16*)(ws + 6400000);     // 6,400,000 fl
  int*   perm2    = (int*)(ws + 12800000);    // 3,200,000 ints (1.6M int2)
  float* degf     = ws + 16000000;            //   100,000
  int*   deg_i    = (int*)(ws + 16100000);    //   100,000  -- memset start
  float* g        = ws + 16200000;            //    64,000
  float* mstats   = ws + 16264000;            //       128
  float* ustats   = ws + 16264128;            //       128  -- memset end (164,256 fl)
  float* maff     = ws + 16264256;            //       128
  float* uaff     = ws + 16264384;            //       128
  int*   flag     = (int*)(ws + 16264512);    //        16
  u16*   Weff     = (u16*)(ws + 16264528);    //     9,216 fl (3*64*96 u16)
  u16*   Wupd     = (u16*)(ws + 16273744);    //     6,144 fl (64*192 u16)
  float* biasv    = ws + 16279888;            //        64
  float* tvv      = ws + 16279952;            //        64
  int*   row_ptr  = (int*)(ws + 16280016);    //   100,001
  int*   cursor   = (int*)(ws + 16380020);    //   100,000
  int*   bsum     = (int*)(ws + 16480020);    //       196
  int*   boff     = (int*)(ws + 16480216);    //       196 -> end 16,480,412 fl

  const int MM_BLOCKS = 2048;
  const int MM_WAVES  = MM_BLOCKS * 4;
  const int UPD_BLOCKS = 782;                 // 3128 waves, ~2 tiles/wave

  k_detect<<<1, 64, 0, stream>>>((const u32*)x, flag);
  hipMemsetAsync(ws + 16100000, 0, 164256*sizeof(float), stream); // deg_i+g+stats
  k_prep<<<3, 64, 0, stream>>>(eW, eb, mW, mb, Weff, flag);
  k_node_emb<<<256, 256, 0, stream>>>(x, nW, nb, hsp, flag);
  k_deg<<<512, 256, 0, stream>>>(ei, deg_i);
  k_scan1<<<196, 256, 0, stream>>>(deg_i, bsum);
  k_scan2<<<1, 256, 0, stream>>>(bsum, boff, row_ptr);
  k_scan3<<<196, 256, 0, stream>>>(deg_i, boff, row_ptr, cursor, degf);
  k_scatter<<<512, 256, 0, stream>>>(ei, cursor, perm2);

  for (int l = 0; l < 3; l++){
    k_msgmm<<<MM_BLOCKS, 256, 0, stream>>>(hsp, ea, row_ptr, perm2, Weff,
                                           aggs, mstats, flag, l, MM_WAVES);
    k_fin<<<1, 64, 0, stream>>>(mstats, mg, mbe, maff, 1.0f/(float)N_EDGES, l*64, flag);
    k_updprep<<<1, 64, 0, stream>>>(uW, ub, maff, Wupd, biasv, tvv, flag, l);
    k_updmm<<<UPD_BLOCKS, 256, 0, stream>>>(hsp, aggs, degf, Wupd, biasv, tvv,
                                            ustats);
    k_fin<<<1, 64, 0, stream>>>(ustats, ug, ube, uaff, 1.0f/(float)N_NODES, l*64, flag);
    k_norm<<<256, 256, 0, stream>>>(aggs, uaff, hsp);
  }

  k_pool<<<128, 256, 0, stream>>>(hsp, bt, g);
  k_read<<<NUM_GRAPHS, 64, 0, stream>>>(g, r1W, r1b, r2W, r2b, d_out, flag);
}